// Round 7
// baseline (98.721 us; speedup 1.0000x reference)
//
#include <hip/hip_runtime.h>

#define N2 4096
#define D 128
#define TAU_INV 10.0f
#define E2SCALE 14.4269504088896340736f   // 10 * log2(e): exp(10x) = exp2(x*E2SCALE)
#define JSL 4                     // j-slices per i-tile row
#define TPW (N2 / (JSL * 128))    // j-tiles per wave = 8 (4 pairs)
#define GEMM_BLOCKS (128 * JSL)   // 512
#define NCLS 10
#define CGRP 16                   // row-groups per class
#define CROWS (N2 / CGRP)         // 256 rows per class block
#define CB (NCLS * CGRP)          // 160 class blocks (scheduled FIRST)

typedef __attribute__((ext_vector_type(8))) short bf16x8;
typedef __attribute__((ext_vector_type(16))) float floatx16;

__device__ __forceinline__ short f2bf(float f) {
    unsigned u = __float_as_uint(f);
    u = (u + 0x7fff + ((u >> 16) & 1)) >> 16;   // RNE
    return (short)u;
}
__device__ __forceinline__ float bf2f(short s) {
    return __uint_as_float(((unsigned)(unsigned short)s) << 16);
}

// Normalize rows of p = concat(z_i, z_j) in fp32, emit bf16 Q.
// One row per 64-thread block. Also zeroes se_g and block 0 zeroes S/T/CNT.
__global__ __launch_bounds__(64) void prep_kernel(const float* __restrict__ zi,
                                                  const float* __restrict__ zj,
                                                  short* __restrict__ qb,
                                                  float* __restrict__ se_g,
                                                  float* __restrict__ S) {   // S,T,CNT contiguous: 1300 floats
    int row = blockIdx.x;
    int lane = threadIdx.x;                    // 64 lanes, 2 floats each
    const float* src = (row < 2048) ? (zi + row * D) : (zj + (row - 2048) * D);
    float2 v = ((const float2*)src)[lane];
    float ss = v.x * v.x + v.y * v.y;
    #pragma unroll
    for (int m = 1; m < 64; m <<= 1) ss += __shfl_xor(ss, m);
    float inv = 1.0f / sqrtf(ss);              // ||p|| ~ sqrt(128) >> eps
    short2 o;
    o.x = f2bf(v.x * inv);
    o.y = f2bf(v.y * inv);
    ((short2*)(qb + row * D))[lane] = o;
    if (lane == 0) se_g[row] = 0.f;
    if (row == 0)
        for (int k = lane; k < NCLS * D + 2 * NCLS; k += 64) S[k] = 0.f;
}

// Grid = 160 class blocks (first) + 512 GEMM blocks.
//
// GEMM block: one 32-row i-tile x one 1024-col j-slice. 4 waves; wave w owns
// j-tiles w+4t, t=0..7, processed as 4 PAIRS with two independent MFMA chains
// (acc0/acc1) interleaved for ILP; next pair's B-loads issue before the exp
// epilogue so VALU time hides L2 latency. MFMA 32x32x16 bf16, K=128 (8 steps).
// A/B frags: lane holds row base+(lane&31), 8 contiguous bf16 at k*16+(lane>>5)*8.
// C/D: col = lane&31, row = (reg&3) + 8*(reg>>2) + 4*(lane>>5).
// Accumulates only se (exp-sum, diagonal excluded; diagonal tile is wave-uniform).
//
// Class block cb (class c, row-group g): masked sums over 256 rows of qb.
// Labels used as VALUES only; all addresses structural -> poison-safe.
__global__ __launch_bounds__(256) void main_kernel(const short* __restrict__ qb,
                                                   const long long* __restrict__ y,
                                                   float* __restrict__ se_g,
                                                   float* __restrict__ S) {
    int tid = threadIdx.x;

    if (blockIdx.x < CB) {
        // ---- class-sum path ----
        int cb = blockIdx.x;                 // 0..159
        int c  = cb / CGRP;                  // 0..9
        int g  = cb % CGRP;                  // 0..15
        int d  = tid & 127;
        int rh = tid >> 7;                   // 0/1
        int r0 = g * CROWS + rh * (CROWS / 2);

        float sS = 0.f, sT = 0.f, cnt = 0.f;
        #pragma unroll 4
        for (int i = 0; i < CROWS / 2; ++i) {
            int r = r0 + i;
            bool m = ((int)y[r & 2047] == c);      // wave-uniform broadcast
            float q = bf2f(qb[r * D + d]);         // coalesced 128B per wave
            sS += m ? q : 0.f;
            sT += m ? q * q : 0.f;
            cnt += m ? 1.f : 0.f;
        }

        __shared__ float shS[256];
        __shared__ float shT[4];
        __shared__ float shC[2];
        shS[tid] = sS;
        #pragma unroll
        for (int m = 1; m < 64; m <<= 1) sT += __shfl_xor(sT, m);
        if ((tid & 63) == 0) shT[tid >> 6] = sT;
        if (d == 0) shC[rh] = cnt;
        __syncthreads();
        if (tid < 128) atomicAdd(&S[c * D + tid], shS[tid] + shS[tid + 128]);
        if (tid == 0) {
            atomicAdd(&S[NCLS * D + c], shT[0] + shT[1] + shT[2] + shT[3]);   // T_c
            atomicAdd(&S[NCLS * D + NCLS + c], shC[0] + shC[1]);              // CNT_c
        }
        return;
    }

    // ---- GEMM path ----
    int gb = blockIdx.x - CB;          // 0..511
    int wave = tid >> 6;
    int lane = tid & 63;
    int col  = lane & 31;
    int half = lane >> 5;
    int it = gb >> 2;                  // 0..127
    int js = gb & (JSL - 1);           // 0..3
    int i0 = it * 32;
    int jbase = js * (N2 / JSL);

    // A fragments for this block's 32 i-rows (reused across all 8 j-tiles)
    const short* ap = qb + (i0 + col) * D + half * 8;
    bf16x8 af[8];
    #pragma unroll
    for (int k = 0; k < 8; ++k) af[k] = *(const bf16x8*)(ap + k * 16);

    float se[16];
    #pragma unroll
    for (int r = 0; r < 16; ++r) se[r] = 0.f;

    const short* bbase = qb + col * D + half * 8;

    // prologue: load B for tiles 0 and 1
    bf16x8 b0[8], b1[8];
    {
        const short* p0 = bbase + (jbase + (wave + 0) * 32) * D;
        const short* p1 = bbase + (jbase + (wave + 4) * 32) * D;
        #pragma unroll
        for (int k = 0; k < 8; ++k) b0[k] = *(const bf16x8*)(p0 + k * 16);
        #pragma unroll
        for (int k = 0; k < 8; ++k) b1[k] = *(const bf16x8*)(p1 + k * 16);
    }

    #pragma unroll
    for (int p = 0; p < TPW / 2; ++p) {
        int j0a = jbase + (wave + 4 * (2 * p)) * 32;
        int j0b = jbase + (wave + 4 * (2 * p + 1)) * 32;

        // two independent MFMA chains, interleaved
        floatx16 acc0, acc1;
        #pragma unroll
        for (int r = 0; r < 16; ++r) { acc0[r] = 0.f; acc1[r] = 0.f; }
        #pragma unroll
        for (int k = 0; k < 8; ++k) {
            acc0 = __builtin_amdgcn_mfma_f32_32x32x16_bf16(af[k], b0[k], acc0, 0, 0, 0);
            acc1 = __builtin_amdgcn_mfma_f32_32x32x16_bf16(af[k], b1[k], acc1, 0, 0, 0);
        }

        // issue next pair's B-loads BEFORE the epilogue (exp hides L2 latency)
        if (p < TPW / 2 - 1) {
            const short* p0 = bbase + (jbase + (wave + 4 * (2 * p + 2)) * 32) * D;
            const short* p1 = bbase + (jbase + (wave + 4 * (2 * p + 3)) * 32) * D;
            #pragma unroll
            for (int k = 0; k < 8; ++k) b0[k] = *(const bf16x8*)(p0 + k * 16);
            #pragma unroll
            for (int k = 0; k < 8; ++k) b1[k] = *(const bf16x8*)(p1 + k * 16);
        }

        // epilogue tile a
        if (j0a == i0) {                      // wave-uniform: diagonal tile
            int jcol = j0a + col;
            #pragma unroll
            for (int r = 0; r < 16; ++r) {
                int rowr = i0 + (r & 3) + 8 * (r >> 2) + 4 * half;
                float e = __builtin_amdgcn_exp2f(acc0[r] * E2SCALE);
                se[r] += (rowr == jcol) ? 0.f : e;
            }
        } else {
            #pragma unroll
            for (int r = 0; r < 16; ++r)
                se[r] += __builtin_amdgcn_exp2f(acc0[r] * E2SCALE);
        }
        // epilogue tile b
        if (j0b == i0) {
            int jcol = j0b + col;
            #pragma unroll
            for (int r = 0; r < 16; ++r) {
                int rowr = i0 + (r & 3) + 8 * (r >> 2) + 4 * half;
                float e = __builtin_amdgcn_exp2f(acc1[r] * E2SCALE);
                se[r] += (rowr == jcol) ? 0.f : e;
            }
        } else {
            #pragma unroll
            for (int r = 0; r < 16; ++r)
                se[r] += __builtin_amdgcn_exp2f(acc1[r] * E2SCALE);
        }
    }

    // reduce across the 32 cols (stay within each 32-lane half) and accumulate
    #pragma unroll
    for (int r = 0; r < 16; ++r) {
        float a = se[r];
        #pragma unroll
        for (int m = 1; m < 32; m <<= 1) a += __shfl_xor(a, m);
        if (col == 0) {
            int rowr = i0 + (r & 3) + 8 * (r >> 2) + 4 * half;
            atomicAdd(&se_g[rowr], a);
        }
    }
}

// loss = (sum_i log se_i  -  sum_c 10*(||S_c||^2 - T_c)/(n_c-1)) / N2
__global__ __launch_bounds__(256) void finish_kernel(const float* __restrict__ se_g,
                                                     const float* __restrict__ S,
                                                     float* __restrict__ out) {
    int tid = threadIdx.x;
    int wave = tid >> 6;
    int lane = tid & 63;

    // positive-pair term: wave w handles classes w, w+4, w+8
    float P = 0.f;
    for (int c = wave; c < NCLS; c += 4) {
        float2 sv = ((const float2*)(S + c * D))[lane];
        float s2 = sv.x * sv.x + sv.y * sv.y;
        #pragma unroll
        for (int m = 1; m < 64; m <<= 1) s2 += __shfl_xor(s2, m);
        float n = S[NCLS * D + NCLS + c];
        P += (n >= 2.0f) ? (s2 - S[NCLS * D + c]) * TAU_INV / (n - 1.0f) : 0.f;
    }

    // denominator term
    float L = 0.f;
    for (int i = tid; i < N2; i += 256) L += __logf(se_g[i]);
    #pragma unroll
    for (int m = 1; m < 64; m <<= 1) L += __shfl_xor(L, m);

    __shared__ float red[8];
    if (lane == 0) { red[wave] = L; red[4 + wave] = P; }
    __syncthreads();
    if (tid == 0) {
        float Ls = red[0] + red[1] + red[2] + red[3];
        float Ps = red[4] + red[5] + red[6] + red[7];
        out[0] = (Ls - Ps) * (1.0f / (float)N2);
    }
}

extern "C" void kernel_launch(void* const* d_in, const int* in_sizes, int n_in,
                              void* d_out, int out_size, void* d_ws, size_t ws_size,
                              hipStream_t stream) {
    const float*     zi = (const float*)d_in[0];
    const float*     zj = (const float*)d_in[1];
    const long long* y  = (const long long*)d_in[2];
    float* out = (float*)d_out;

    char* ws = (char*)d_ws;
    short* qb   = (short*)ws;                               // 4096*128*2B = 1 MB
    float* se_g = (float*)(ws + N2 * D * sizeof(short));    // 16 KB
    float* S    = se_g + N2;                                // S[10][128] + T[10] + CNT[10] = 1300 f32

    prep_kernel<<<N2, 64, 0, stream>>>(zi, zj, qb, se_g, S);
    main_kernel<<<CB + GEMM_BLOCKS, 256, 0, stream>>>(qb, y, se_g, S);
    finish_kernel<<<1, 256, 0, stream>>>(se_g, S, out);
}